// Round 2
// baseline (1927.922 us; speedup 1.0000x reference)
//
#include <hip/hip_runtime.h>
#include <hip/hip_bf16.h>
#include <math.h>

// Transformer encoder, B=4 S=1024 D=1024 H=16 DH=64 L=4 MLP=4096.
// bf16 MFMA (16x16x32) for all GEMMs + attention; fp32 LN/RoPE/softmax/residual.
// Weights converted+transposed to bf16 [N][K] per layer (stream-serial reuse).

#define TD 1024
#define TH 16
#define TDH 64
#define TL 4
#define TMLP 4096
#define TB 4
#define TS 1024
#define TM (TB*TS)  // 4096 rows

typedef __attribute__((ext_vector_type(8))) short short8;
typedef __attribute__((ext_vector_type(4))) float f32x4;
typedef __attribute__((ext_vector_type(4))) unsigned short us4;
typedef __attribute__((ext_vector_type(2))) unsigned short us2;

__device__ __forceinline__ float bf2f(unsigned short u) {
  union { unsigned int i; float f; } x; x.i = ((unsigned int)u) << 16; return x.f;
}
// round-to-nearest-even f32 -> bf16 (finite inputs only)
__device__ __forceinline__ unsigned short f2bf(float f) {
  unsigned int x = __float_as_uint(f);
  unsigned int r = (x + 0x7FFFu + ((x >> 16) & 1u)) >> 16;
  return (unsigned short)r;
}

#if defined(__has_builtin)
#if __has_builtin(__builtin_amdgcn_global_load_lds)
#define TE_HAS_GLL 1
#endif
#endif

__device__ __forceinline__ void stage16(void* lds, const void* g) {
#ifdef TE_HAS_GLL
  __builtin_amdgcn_global_load_lds(
      (const __attribute__((address_space(1))) void*)g,
      (__attribute__((address_space(3))) void*)lds, 16, 0, 0);
#else
  *(short8*)lds = *(const short8*)g;   // fallback: reg round-trip
#endif
}

#define MFMA_BF16(a,b,c) __builtin_amdgcn_mfma_f32_16x16x32_bf16((a),(b),(c),0,0,0)

// ---------------- RoPE / xpos tables: tab[s*32+i] = {cos, sin, scale*0.125, 1/scale}
__global__ __launch_bounds__(256)
void te_tab(float4* __restrict__ tab) {
  int idx = blockIdx.x * 256 + threadIdx.x;   // TS*32 = 32768
  int s = idx >> 5, i = idx & 31;
  float inv = powf(10000.0f, -(2.0f * (float)i) / 64.0f);
  float fr = (float)s * inv;
  float c = cosf(fr), sn = sinf(fr);
  float base = (2.0f * (float)i + 0.4f * 64.0f) / (1.4f * 64.0f);
  float p = ((float)s - 512.0f) / 512.0f;
  float scl = powf(base, p);
  float4 t;
  t.x = c; t.y = sn; t.z = scl * 0.125f; t.w = 1.0f / scl;
  tab[idx] = t;
}

// ---------------- weight convert + transpose: W[K][N] f32 -> Wt[N][K] bf16
__global__ __launch_bounds__(256)
void te_transpose_cvt(const float* __restrict__ src, unsigned short* __restrict__ dst,
                      int K, int N) {
  __shared__ float tile[32][33];
  int n0 = blockIdx.x * 32, k0 = blockIdx.y * 32;
  int tx = threadIdx.x, ty = threadIdx.y;
  #pragma unroll
  for (int j = 0; j < 4; ++j)
    tile[ty + 8*j][tx] = src[(size_t)(k0 + ty + 8*j) * N + n0 + tx];
  __syncthreads();
  #pragma unroll
  for (int j = 0; j < 4; ++j)
    dst[(size_t)(n0 + ty + 8*j) * K + k0 + tx] = f2bf(tile[tx][ty + 8*j]);
}

// ---------------- LayerNorm over D=1024, one block per row
template<int OUTBF>  // 1: bf16 out, 0: f32 out
__global__ __launch_bounds__(256)
void te_ln(const float* __restrict__ in, const float* __restrict__ w,
           const float* __restrict__ b, void* __restrict__ outp) {
  int row = blockIdx.x, t = threadIdx.x;
  float4 v = ((const float4*)(in + (size_t)row * TD))[t];
  float s = v.x + v.y + v.z + v.w;
  float sq = v.x*v.x + v.y*v.y + v.z*v.z + v.w*v.w;
  #pragma unroll
  for (int o = 1; o < 64; o <<= 1) { s += __shfl_xor(s, o); sq += __shfl_xor(sq, o); }
  __shared__ float red[8];
  int wv = t >> 6;
  if ((t & 63) == 0) { red[wv] = s; red[4 + wv] = sq; }
  __syncthreads();
  s  = red[0] + red[1] + red[2] + red[3];
  sq = red[4] + red[5] + red[6] + red[7];
  float mean = s * (1.0f / TD);
  float rstd = rsqrtf(sq * (1.0f / TD) - mean * mean + 1e-5f);
  float4 w4 = ((const float4*)w)[t];
  float4 b4 = ((const float4*)b)[t];
  float r0 = (v.x - mean) * rstd * w4.x + b4.x;
  float r1 = (v.y - mean) * rstd * w4.y + b4.y;
  float r2 = (v.z - mean) * rstd * w4.z + b4.z;
  float r3 = (v.w - mean) * rstd * w4.w + b4.w;
  if (OUTBF) {
    us4 pk; pk[0] = f2bf(r0); pk[1] = f2bf(r1); pk[2] = f2bf(r2); pk[3] = f2bf(r3);
    ((us4*)outp)[(size_t)row * (TD/4) + t] = pk;
  } else {
    float4 o; o.x = r0; o.y = r1; o.z = r2; o.w = r3;
    ((float4*)outp)[(size_t)row * (TD/4) + t] = o;
  }
}

// ---------------- GEMM: C[M,N] = A[M,K](bf16) @ Bt[N,K](bf16)^T, m97-style 128x128x32
// MODE 0: out_bf16 = acc + bias
// MODE 1: out_f32  = resid + acc + bias      (residual-stream update)
// MODE 2: out_bf16 = silu(gate) * (acc+bias) (gate = h@w1+b1, bf16)
template<int MODE>
__global__ __launch_bounds__(256)
void te_gemm(const unsigned short* __restrict__ A, const unsigned short* __restrict__ Bt,
             const float* __restrict__ bias, const float* resid,
             const unsigned short* __restrict__ gate, void* outp,
             int M, int N, int K) {
  __shared__ short As[128 * 32];
  __shared__ short Bs[128 * 32];
  int bm = blockIdx.x, bn = blockIdx.y;
  int t = threadIdx.x;
  int lane = t & 63, w = t >> 6;
  int wr = w >> 1, wc = w & 1;
  int lr = lane & 15, lk = lane >> 4;
  f32x4 acc[4][4] = {};

  int srow = t >> 2, scol = (t & 3) * 8;
  const short* Ap = (const short*)A + (size_t)(bm * 128 + srow) * K + scol;
  const short* Bp = (const short*)Bt + (size_t)(bn * 128 + srow) * K + scol;
  short* Al = As + t * 8;
  short* Bl = Bs + t * 8;
  const size_t stride64 = (size_t)64 * K;
  int nk = K >> 5;
  for (int kt = 0; kt < nk; ++kt) {
    __syncthreads();
    stage16(Al,        Ap);
    stage16(Al + 2048, Ap + stride64);
    stage16(Bl,        Bp);
    stage16(Bl + 2048, Bp + stride64);
    Ap += 32; Bp += 32;
    __syncthreads();
    short8 af[4], bfv[4];
    #pragma unroll
    for (int mi = 0; mi < 4; ++mi)
      af[mi] = *(const short8*)&As[(wr*64 + mi*16 + lr) * 32 + lk*8];
    #pragma unroll
    for (int nj = 0; nj < 4; ++nj)
      bfv[nj] = *(const short8*)&Bs[(wc*64 + nj*16 + lr) * 32 + lk*8];
    #pragma unroll
    for (int mi = 0; mi < 4; ++mi)
      #pragma unroll
      for (int nj = 0; nj < 4; ++nj)
        acc[mi][nj] = MFMA_BF16(af[mi], bfv[nj], acc[mi][nj]);
  }
  #pragma unroll
  for (int mi = 0; mi < 4; ++mi) {
    #pragma unroll
    for (int nj = 0; nj < 4; ++nj) {
      int col = bn*128 + wc*64 + nj*16 + lr;
      float bv = bias[col];
      #pragma unroll
      for (int r = 0; r < 4; ++r) {
        int row = bm*128 + wr*64 + mi*16 + lk*4 + r;
        size_t o = (size_t)row * N + col;
        float val = acc[mi][nj][r] + bv;
        if (MODE == 0) {
          ((unsigned short*)outp)[o] = f2bf(val);
        } else if (MODE == 1) {
          ((float*)outp)[o] = resid[o] + val;
        } else {
          float a = bf2f(gate[o]);
          float sg = a / (1.0f + __expf(-a));
          ((unsigned short*)outp)[o] = f2bf(sg * val);
        }
      }
    }
  }
}

// ---------------- RoPE: qkv bf16 [M][3D] -> roped q,k bf16 [M][D] (0.125 folded into q)
__global__ __launch_bounds__(256)
void te_rope(const unsigned short* __restrict__ qkv, const float4* __restrict__ tab,
             unsigned short* __restrict__ qb, unsigned short* __restrict__ kb) {
  int idx = blockIdx.x * 256 + threadIdx.x;  // TM*TH*32
  int i = idx & 31;
  int h = (idx >> 5) & 15;
  int row = idx >> 9;
  int s = row & (TS - 1);
  float4 t4 = tab[(s << 5) + i];
  size_t base = (size_t)row * (3*TD) + h * TDH + 2*i;
  us2 qp = *(const us2*)&qkv[base];
  us2 kp = *(const us2*)&qkv[base + TD];
  float qe = bf2f(qp[0]), qo = bf2f(qp[1]);
  float ke = bf2f(kp[0]), ko = bf2f(kp[1]);
  size_t ob = (size_t)row * TD + h * TDH + 2*i;
  us2 qo2, ko2;
  qo2[0] = f2bf((qe * t4.x - qo * t4.y) * t4.z);
  qo2[1] = f2bf((qo * t4.x + qe * t4.y) * t4.z);
  ko2[0] = f2bf((ke * t4.x - ko * t4.y) * t4.w);
  ko2[1] = f2bf((ko * t4.x + ke * t4.y) * t4.w);
  *(us2*)&qb[ob] = qo2;
  *(us2*)&kb[ob] = ko2;
}

// ---------------- flash-style attention: block = (qtile of 64 rows) x (b,h); 4 waves x 16 rows
__global__ __launch_bounds__(256)
void te_attn(const unsigned short* __restrict__ qb, const unsigned short* __restrict__ kb,
             const unsigned short* __restrict__ qkv, unsigned short* __restrict__ y) {
  __shared__ char Ks[8192];      // K tile [64 kv][64 dh] bf16, XOR-swizzled rows
  __shared__ char Vs[8192];      // V^T tile [64 dh][64 kv] bf16, XOR-swizzled rows
  __shared__ char Ps[4][2048];   // per-wave P [16 q][64 kv] bf16, XOR-swizzled
  int qt = blockIdx.x;           // 0..15
  int bh = blockIdx.y;           // 0..63
  int b = bh >> 4, h = bh & 15;
  int t = threadIdx.x, lane = t & 63, w = t >> 6;
  int lq = lane & 15, lg = lane >> 4;

  const unsigned short* vptr = qkv + 2*TD;  // v columns, row stride 3*TD

  int qrow = b*TS + qt*64 + w*16 + lq;
  short8 aq0 = *(const short8*)&qb[(size_t)qrow*TD + h*TDH + lg*8];
  short8 aq1 = *(const short8*)&qb[(size_t)qrow*TD + h*TDH + 32 + lg*8];

  f32x4 oacc[4] = {};
  float rm[4] = {-3e38f, -3e38f, -3e38f, -3e38f};
  float rl[4] = {0.f, 0.f, 0.f, 0.f};

  int srr = t >> 3;          // 0..31
  int scb = (t & 7) * 8;     // 0..56

  for (int kt = 0; kt < TS/64; ++kt) {
    int kbase = b*TS + kt*64;
    __syncthreads();
    // stage K tile (vector copy, swizzled)
    #pragma unroll
    for (int half = 0; half < 2; ++half) {
      int row = srr + half*32;
      short8 d = *(const short8*)&kb[(size_t)(kbase + row)*TD + h*TDH + scb];
      int off = (row*128 + scb*2) ^ ((row & 7) << 4);
      *(short8*)&Ks[off] = d;
    }
    // stage V transposed (gather; L1/L2 absorbs repeats across q-tiles)
    #pragma unroll
    for (int half = 0; half < 2; ++half) {
      int dh = srr + half*32;
      short8 d;
      #pragma unroll
      for (int i = 0; i < 8; ++i)
        d[i] = (short)vptr[(size_t)(kbase + scb + i)*(3*TD) + h*TDH + dh];
      int off = (dh*128 + scb*2) ^ ((dh & 7) << 4);
      *(short8*)&Vs[off] = d;
    }
    __syncthreads();
    // scores: 16 q rows x 64 kv cols per wave
    f32x4 sc[4];
    #pragma unroll
    for (int nj = 0; nj < 4; ++nj) {
      int row = nj*16 + lq;
      int sw = (row & 7) << 4;
      short8 b0 = *(const short8*)&Ks[(row*128 + lg*16) ^ sw];
      short8 b1 = *(const short8*)&Ks[(row*128 + 64 + lg*16) ^ sw];
      f32x4 c = {};
      c = MFMA_BF16(aq0, b0, c);
      c = MFMA_BF16(aq1, b1, c);
      sc[nj] = c;
    }
    // online softmax (lane handles q rows lg*4+r; reduce across 16-lane group)
    float mn[4], al[4];
    #pragma unroll
    for (int r = 0; r < 4; ++r) {
      float x = fmaxf(fmaxf(sc[0][r], sc[1][r]), fmaxf(sc[2][r], sc[3][r]));
      #pragma unroll
      for (int o = 1; o < 16; o <<= 1) x = fmaxf(x, __shfl_xor(x, o));
      mn[r] = fmaxf(rm[r], x);
      al[r] = __expf(rm[r] - mn[r]);
      rm[r] = mn[r];
    }
    #pragma unroll
    for (int nj = 0; nj < 4; ++nj)
      #pragma unroll
      for (int r = 0; r < 4; ++r)
        sc[nj][r] = __expf(sc[nj][r] - mn[r]);
    #pragma unroll
    for (int r = 0; r < 4; ++r) {
      float x = sc[0][r] + sc[1][r] + sc[2][r] + sc[3][r];
      #pragma unroll
      for (int o = 1; o < 16; o <<= 1) x += __shfl_xor(x, o);
      rl[r] = rl[r] * al[r] + x;
    }
    #pragma unroll
    for (int d0 = 0; d0 < 4; ++d0)
      #pragma unroll
      for (int r = 0; r < 4; ++r)
        oacc[d0][r] *= al[r];
    // write P (C-layout) to per-wave LDS, re-read as A-fragments
    #pragma unroll
    for (int nj = 0; nj < 4; ++nj)
      #pragma unroll
      for (int r = 0; r < 4; ++r) {
        int row = lg*4 + r;
        int off = (row*128 + (nj*16 + lq)*2) ^ ((row & 7) << 4);
        *(short*)&Ps[w][off] = (short)f2bf(sc[nj][r]);
      }
    short8 pa0, pa1;
    {
      int sw = (lq & 7) << 4;
      pa0 = *(const short8*)&Ps[w][(lq*128 + lg*16) ^ sw];
      pa1 = *(const short8*)&Ps[w][(lq*128 + 64 + lg*16) ^ sw];
    }
    // PV
    #pragma unroll
    for (int d0 = 0; d0 < 4; ++d0) {
      int row = d0*16 + lq;
      int sw = (row & 7) << 4;
      short8 b0 = *(const short8*)&Vs[(row*128 + lg*16) ^ sw];
      short8 b1 = *(const short8*)&Vs[(row*128 + 64 + lg*16) ^ sw];
      oacc[d0] = MFMA_BF16(pa0, b0, oacc[d0]);
      oacc[d0] = MFMA_BF16(pa1, b1, oacc[d0]);
    }
  }
  #pragma unroll
  for (int d0 = 0; d0 < 4; ++d0)
    #pragma unroll
    for (int r = 0; r < 4; ++r) {
      int row = b*TS + qt*64 + w*16 + lg*4 + r;
      float val = oacc[d0][r] / rl[r];
      y[(size_t)row*TD + h*TDH + d0*16 + lq] = f2bf(val);
    }
}

extern "C" void kernel_launch(void* const* d_in, const int* in_sizes, int n_in,
                              void* d_out, int out_size, void* d_ws, size_t ws_size,
                              hipStream_t stream) {
  const float* x_in = (const float*)d_in[0];
  const float* ln1w = (const float*)d_in[1];
  const float* ln1b = (const float*)d_in[2];
  const float* wqkv = (const float*)d_in[3];
  const float* bqkv = (const float*)d_in[4];
  const float* wo   = (const float*)d_in[5];
  const float* bo   = (const float*)d_in[6];
  const float* ln2w = (const float*)d_in[7];
  const float* ln2b = (const float*)d_in[8];
  const float* w1   = (const float*)d_in[9];
  const float* b1   = (const float*)d_in[10];
  const float* w2   = (const float*)d_in[11];
  const float* b2   = (const float*)d_in[12];
  const float* wout = (const float*)d_in[13];
  const float* bout = (const float*)d_in[14];
  const float* flnw = (const float*)d_in[15];
  const float* flnb = (const float*)d_in[16];

  char* ws = (char*)d_ws;
  size_t off = 0;
  auto alloc = [&](size_t bytes) -> void* {
    void* p = ws + off;
    off += (bytes + 255) & ~(size_t)255;
    return p;
  };
  // per-layer weight buffers (stream-serial reuse across layers)
  unsigned short* wqkv_t = (unsigned short*)alloc((size_t)3*TD*TD*2);
  unsigned short* wo_t   = (unsigned short*)alloc((size_t)TD*TD*2);
  unsigned short* w1_t   = (unsigned short*)alloc((size_t)TMLP*TD*2);
  unsigned short* w2_t   = (unsigned short*)alloc((size_t)TMLP*TD*2);
  unsigned short* wout_t = (unsigned short*)alloc((size_t)TD*TMLP*2);
  float*          x      = (float*)alloc((size_t)TM*TD*4);
  unsigned short* nrm    = (unsigned short*)alloc((size_t)TM*TD*2);
  unsigned short* u1     = (unsigned short*)alloc((size_t)TM*TMLP*2); // qkv | mlp-a
  unsigned short* qbuf   = (unsigned short*)alloc((size_t)TM*TD*2);
  unsigned short* kbuf   = (unsigned short*)alloc((size_t)TM*TD*2);
  unsigned short* u2     = (unsigned short*)alloc((size_t)TM*TMLP*2); // y | mlp-g
  float4*         tab    = (float4*)alloc((size_t)TS*32*sizeof(float4));
  // total ~143.3 MB

  dim3 blk256(256);
  dim3 tblk(32, 8);
  te_tab<<<dim3(TS*32/256), blk256, 0, stream>>>(tab);
  hipMemcpyAsync(x, x_in, (size_t)TM*TD*4, hipMemcpyDeviceToDevice, stream);

  for (int l = 0; l < TL; ++l) {
    te_transpose_cvt<<<dim3(3*TD/32, TD/32), tblk, 0, stream>>>(
        wqkv + (size_t)l*TD*3*TD, wqkv_t, TD, 3*TD);
    te_transpose_cvt<<<dim3(TD/32, TD/32), tblk, 0, stream>>>(
        wo + (size_t)l*TD*TD, wo_t, TD, TD);
    te_transpose_cvt<<<dim3(TMLP/32, TD/32), tblk, 0, stream>>>(
        w1 + (size_t)l*TD*TMLP, w1_t, TD, TMLP);
    te_transpose_cvt<<<dim3(TMLP/32, TD/32), tblk, 0, stream>>>(
        w2 + (size_t)l*TD*TMLP, w2_t, TD, TMLP);
    te_transpose_cvt<<<dim3(TD/32, TMLP/32), tblk, 0, stream>>>(
        wout + (size_t)l*TMLP*TD, wout_t, TMLP, TD);

    te_ln<1><<<dim3(TM), blk256, 0, stream>>>(x, ln1w + l*TD, ln1b + l*TD, nrm);
    te_gemm<0><<<dim3(TM/128, 3*TD/128), blk256, 0, stream>>>(
        nrm, wqkv_t, bqkv + l*3*TD, nullptr, nullptr, u1, TM, 3*TD, TD);
    te_rope<<<dim3(TM*TH*32/256), blk256, 0, stream>>>(u1, tab, qbuf, kbuf);
    te_attn<<<dim3(TS/64, TB*TH), blk256, 0, stream>>>(qbuf, kbuf, u1, u2);
    te_gemm<1><<<dim3(TM/128, TD/128), blk256, 0, stream>>>(
        u2, wo_t, bo + l*TD, x, nullptr, x, TM, TD, TD);
    te_ln<1><<<dim3(TM), blk256, 0, stream>>>(x, ln2w + l*TD, ln2b + l*TD, nrm);
    te_gemm<0><<<dim3(TM/128, TMLP/128), blk256, 0, stream>>>(
        nrm, w1_t, b1 + l*TMLP, nullptr, nullptr, u1, TM, TMLP, TD);
    te_gemm<2><<<dim3(TM/128, TMLP/128), blk256, 0, stream>>>(
        nrm, w2_t, b2 + l*TMLP, nullptr, u1, u2, TM, TMLP, TD);
    te_gemm<1><<<dim3(TM/128, TD/128), blk256, 0, stream>>>(
        u2, wout_t, bout + l*TD, x, nullptr, x, TM, TD, TMLP);
  }
  te_ln<0><<<dim3(TM), blk256, 0, stream>>>(x, flnw, flnb, (float*)d_out);

  (void)in_sizes; (void)n_in; (void)out_size; (void)ws_size;
}

// Round 3
// 1725.815 us; speedup vs baseline: 1.1171x; 1.1171x over previous
//
#include <hip/hip_runtime.h>
#include <hip/hip_bf16.h>
#include <math.h>

// Transformer encoder, B=4 S=1024 D=1024 H=16 DH=64 L=4 MLP=4096.
// bf16 MFMA (16x16x32) for all GEMMs + attention; fp32 LN/RoPE/softmax/residual.
// R2: GEMM rebuilt as BK=64 double-buffered 2-phase (stage next || compute cur),
//     chunk-XOR LDS swizzle (pre-swizzled global source + swizzled ds_read).

#define TD 1024
#define TH 16
#define TDH 64
#define TL 4
#define TMLP 4096
#define TB 4
#define TS 1024
#define TM (TB*TS)  // 4096 rows

typedef __attribute__((ext_vector_type(8))) short short8;
typedef __attribute__((ext_vector_type(4))) float f32x4;
typedef __attribute__((ext_vector_type(4))) unsigned short us4;
typedef __attribute__((ext_vector_type(2))) unsigned short us2;

__device__ __forceinline__ float bf2f(unsigned short u) {
  union { unsigned int i; float f; } x; x.i = ((unsigned int)u) << 16; return x.f;
}
// round-to-nearest-even f32 -> bf16 (finite inputs only)
__device__ __forceinline__ unsigned short f2bf(float f) {
  unsigned int x = __float_as_uint(f);
  unsigned int r = (x + 0x7FFFu + ((x >> 16) & 1u)) >> 16;
  return (unsigned short)r;
}

#if defined(__has_builtin)
#if __has_builtin(__builtin_amdgcn_global_load_lds)
#define TE_HAS_GLL 1
#endif
#endif

__device__ __forceinline__ void stage16(void* lds, const void* g) {
#ifdef TE_HAS_GLL
  __builtin_amdgcn_global_load_lds(
      (const __attribute__((address_space(1))) void*)g,
      (__attribute__((address_space(3))) void*)lds, 16, 0, 0);
#else
  *(short8*)lds = *(const short8*)g;   // fallback: reg round-trip
#endif
}

#define MFMA_BF16(a,b,c) __builtin_amdgcn_mfma_f32_16x16x32_bf16((a),(b),(c),0,0,0)

// ---------------- RoPE / xpos tables: tab[s*32+i] = {cos, sin, scale*0.125, 1/scale}
__global__ __launch_bounds__(256)
void te_tab(float4* __restrict__ tab) {
  int idx = blockIdx.x * 256 + threadIdx.x;   // TS*32 = 32768
  int s = idx >> 5, i = idx & 31;
  float inv = powf(10000.0f, -(2.0f * (float)i) / 64.0f);
  float fr = (float)s * inv;
  float c = cosf(fr), sn = sinf(fr);
  float base = (2.0f * (float)i + 0.4f * 64.0f) / (1.4f * 64.0f);
  float p = ((float)s - 512.0f) / 512.0f;
  float scl = powf(base, p);
  float4 t;
  t.x = c; t.y = sn; t.z = scl * 0.125f; t.w = 1.0f / scl;
  tab[idx] = t;
}

// ---------------- weight convert + transpose: W[K][N] f32 -> Wt[N][K] bf16
__global__ __launch_bounds__(256)
void te_transpose_cvt(const float* __restrict__ src, unsigned short* __restrict__ dst,
                      int K, int N) {
  __shared__ float tile[32][33];
  int n0 = blockIdx.x * 32, k0 = blockIdx.y * 32;
  int tx = threadIdx.x, ty = threadIdx.y;
  #pragma unroll
  for (int j = 0; j < 4; ++j)
    tile[ty + 8*j][tx] = src[(size_t)(k0 + ty + 8*j) * N + n0 + tx];
  __syncthreads();
  #pragma unroll
  for (int j = 0; j < 4; ++j)
    dst[(size_t)(n0 + ty + 8*j) * K + k0 + tx] = f2bf(tile[tx][ty + 8*j]);
}

// ---------------- LayerNorm over D=1024, one block per row
template<int OUTBF>  // 1: bf16 out, 0: f32 out
__global__ __launch_bounds__(256)
void te_ln(const float* __restrict__ in, const float* __restrict__ w,
           const float* __restrict__ b, void* __restrict__ outp) {
  int row = blockIdx.x, t = threadIdx.x;
  float4 v = ((const float4*)(in + (size_t)row * TD))[t];
  float s = v.x + v.y + v.z + v.w;
  float sq = v.x*v.x + v.y*v.y + v.z*v.z + v.w*v.w;
  #pragma unroll
  for (int o = 1; o < 64; o <<= 1) { s += __shfl_xor(s, o); sq += __shfl_xor(sq, o); }
  __shared__ float red[8];
  int wv = t >> 6;
  if ((t & 63) == 0) { red[wv] = s; red[4 + wv] = sq; }
  __syncthreads();
  s  = red[0] + red[1] + red[2] + red[3];
  sq = red[4] + red[5] + red[6] + red[7];
  float mean = s * (1.0f / TD);
  float rstd = rsqrtf(sq * (1.0f / TD) - mean * mean + 1e-5f);
  float4 w4 = ((const float4*)w)[t];
  float4 b4 = ((const float4*)b)[t];
  float r0 = (v.x - mean) * rstd * w4.x + b4.x;
  float r1 = (v.y - mean) * rstd * w4.y + b4.y;
  float r2 = (v.z - mean) * rstd * w4.z + b4.z;
  float r3 = (v.w - mean) * rstd * w4.w + b4.w;
  if (OUTBF) {
    us4 pk; pk[0] = f2bf(r0); pk[1] = f2bf(r1); pk[2] = f2bf(r2); pk[3] = f2bf(r3);
    ((us4*)outp)[(size_t)row * (TD/4) + t] = pk;
  } else {
    float4 o; o.x = r0; o.y = r1; o.z = r2; o.w = r3;
    ((float4*)outp)[(size_t)row * (TD/4) + t] = o;
  }
}

// ---------------- GEMM: C[M,N] = A[M,K](bf16) @ Bt[N,K](bf16)^T
// 128x128 tile, BK=64, double-buffered LDS, 2-phase schedule:
//   stage(next tile) || ds_read+MFMA(cur tile) ; one barrier per K-step.
// LDS layout per tile: row-major [128][64] bf16 with 16B-chunk XOR swizzle
//   chunk' = chunk ^ (row&7); applied on the GLOBAL source (gll writes linear)
//   and on the ds_read address (both-sides involution).
// MODE 0: out_bf16 = acc + bias
// MODE 1: out_f32  = resid + acc + bias      (residual-stream update)
// MODE 2: out_bf16 = silu(gate) * (acc+bias) (gate = h@w1+b1, bf16)
template<int MODE>
__global__ __launch_bounds__(256)
void te_gemm(const unsigned short* __restrict__ A, const unsigned short* __restrict__ Bt,
             const float* __restrict__ bias, const float* resid,
             const unsigned short* __restrict__ gate, void* outp,
             int M, int N, int K) {
  __shared__ short As[2][128 * 64];
  __shared__ short Bs[2][128 * 64];
  int bm = blockIdx.x, bn = blockIdx.y;
  int t = threadIdx.x;
  int lane = t & 63, w = t >> 6;
  int wr = w >> 1, wc = w & 1;
  int lr = lane & 15, lk = lane >> 4;
  f32x4 acc[4][4] = {};

  // staging map: thread t, round j: 16B chunk m = j*256+t; row=m>>3, c=m&7;
  // global source col-chunk = c ^ (row&7)  (pre-swizzle so linear LDS = swizzled)
  const short* Abase = (const short*)A + (size_t)(bm * 128) * K;
  const short* Bbase = (const short*)Bt + (size_t)(bn * 128) * K;
  int srow[4], scol[4];
  #pragma unroll
  for (int j = 0; j < 4; ++j) {
    int m = j * 256 + t;
    int r = m >> 3, c = m & 7;
    srow[j] = r;
    scol[j] = (c ^ (r & 7)) * 8;
  }

  auto stage_tile = [&](int buf, int k0) {
    #pragma unroll
    for (int j = 0; j < 4; ++j) {
      stage16(&As[buf][j * 2048 + t * 8], Abase + (size_t)srow[j] * K + k0 + scol[j]);
      stage16(&Bs[buf][j * 2048 + t * 8], Bbase + (size_t)srow[j] * K + k0 + scol[j]);
    }
  };

  auto compute_tile = [&](int buf) {
    #pragma unroll
    for (int ks = 0; ks < 2; ++ks) {
      short8 af[4], bfv[4];
      #pragma unroll
      for (int mi = 0; mi < 4; ++mi) {
        int row = wr * 64 + mi * 16 + lr;
        int cc = (ks * 4 + lk) ^ (row & 7);
        af[mi] = *(const short8*)&As[buf][row * 64 + cc * 8];
      }
      #pragma unroll
      for (int nj = 0; nj < 4; ++nj) {
        int row = wc * 64 + nj * 16 + lr;
        int cc = (ks * 4 + lk) ^ (row & 7);
        bfv[nj] = *(const short8*)&Bs[buf][row * 64 + cc * 8];
      }
      #pragma unroll
      for (int mi = 0; mi < 4; ++mi)
        #pragma unroll
        for (int nj = 0; nj < 4; ++nj)
          acc[mi][nj] = MFMA_BF16(af[mi], bfv[nj], acc[mi][nj]);
    }
  };

  int nk = K >> 6;
  stage_tile(0, 0);
  __syncthreads();           // vmcnt(0) drain + barrier: tile 0 ready
  int cur = 0;
  for (int kt = 0; kt < nk; ++kt) {
    if (kt + 1 < nk) stage_tile(cur ^ 1, (kt + 1) << 6);  // issue next-tile loads first
    compute_tile(cur);                                    // overlap with loads in flight
    __syncthreads();         // vmcnt(0): next tile landed; barrier: cur consumed
    cur ^= 1;
  }

  #pragma unroll
  for (int mi = 0; mi < 4; ++mi) {
    #pragma unroll
    for (int nj = 0; nj < 4; ++nj) {
      int col = bn*128 + wc*64 + nj*16 + lr;
      float bv = bias[col];
      #pragma unroll
      for (int r = 0; r < 4; ++r) {
        int row = bm*128 + wr*64 + mi*16 + lk*4 + r;
        size_t o = (size_t)row * N + col;
        float val = acc[mi][nj][r] + bv;
        if (MODE == 0) {
          ((unsigned short*)outp)[o] = f2bf(val);
        } else if (MODE == 1) {
          ((float*)outp)[o] = resid[o] + val;
        } else {
          float a = bf2f(gate[o]);
          float sg = a / (1.0f + __expf(-a));
          ((unsigned short*)outp)[o] = f2bf(sg * val);
        }
      }
    }
  }
}

// ---------------- RoPE: qkv bf16 [M][3D] -> roped q,k bf16 [M][D] (0.125 folded into q)
__global__ __launch_bounds__(256)
void te_rope(const unsigned short* __restrict__ qkv, const float4* __restrict__ tab,
             unsigned short* __restrict__ qb, unsigned short* __restrict__ kb) {
  int idx = blockIdx.x * 256 + threadIdx.x;  // TM*TH*32
  int i = idx & 31;
  int h = (idx >> 5) & 15;
  int row = idx >> 9;
  int s = row & (TS - 1);
  float4 t4 = tab[(s << 5) + i];
  size_t base = (size_t)row * (3*TD) + h * TDH + 2*i;
  us2 qp = *(const us2*)&qkv[base];
  us2 kp = *(const us2*)&qkv[base + TD];
  float qe = bf2f(qp[0]), qo = bf2f(qp[1]);
  float ke = bf2f(kp[0]), ko = bf2f(kp[1]);
  size_t ob = (size_t)row * TD + h * TDH + 2*i;
  us2 qo2, ko2;
  qo2[0] = f2bf((qe * t4.x - qo * t4.y) * t4.z);
  qo2[1] = f2bf((qo * t4.x + qe * t4.y) * t4.z);
  ko2[0] = f2bf((ke * t4.x - ko * t4.y) * t4.w);
  ko2[1] = f2bf((ko * t4.x + ke * t4.y) * t4.w);
  *(us2*)&qb[ob] = qo2;
  *(us2*)&kb[ob] = ko2;
}

// ---------------- flash-style attention: block = (qtile of 64 rows) x (b,h); 4 waves x 16 rows
__global__ __launch_bounds__(256)
void te_attn(const unsigned short* __restrict__ qb, const unsigned short* __restrict__ kb,
             const unsigned short* __restrict__ qkv, unsigned short* __restrict__ y) {
  __shared__ char Ks[8192];      // K tile [64 kv][64 dh] bf16, XOR-swizzled rows
  __shared__ char Vs[8192];      // V^T tile [64 dh][64 kv] bf16, XOR-swizzled rows
  __shared__ char Ps[4][2048];   // per-wave P [16 q][64 kv] bf16, XOR-swizzled
  int qt = blockIdx.x;           // 0..15
  int bh = blockIdx.y;           // 0..63
  int b = bh >> 4, h = bh & 15;
  int t = threadIdx.x, lane = t & 63, w = t >> 6;
  int lq = lane & 15, lg = lane >> 4;

  const unsigned short* vptr = qkv + 2*TD;  // v columns, row stride 3*TD

  int qrow = b*TS + qt*64 + w*16 + lq;
  short8 aq0 = *(const short8*)&qb[(size_t)qrow*TD + h*TDH + lg*8];
  short8 aq1 = *(const short8*)&qb[(size_t)qrow*TD + h*TDH + 32 + lg*8];

  f32x4 oacc[4] = {};
  float rm[4] = {-3e38f, -3e38f, -3e38f, -3e38f};
  float rl[4] = {0.f, 0.f, 0.f, 0.f};

  int srr = t >> 3;          // 0..31
  int scb = (t & 7) * 8;     // 0..56

  for (int kt = 0; kt < TS/64; ++kt) {
    int kbase = b*TS + kt*64;
    __syncthreads();
    // stage K tile (vector copy, swizzled)
    #pragma unroll
    for (int half = 0; half < 2; ++half) {
      int row = srr + half*32;
      short8 d = *(const short8*)&kb[(size_t)(kbase + row)*TD + h*TDH + scb];
      int off = (row*128 + scb*2) ^ ((row & 7) << 4);
      *(short8*)&Ks[off] = d;
    }
    // stage V transposed (gather; L1/L2 absorbs repeats across q-tiles)
    #pragma unroll
    for (int half = 0; half < 2; ++half) {
      int dh = srr + half*32;
      short8 d;
      #pragma unroll
      for (int i = 0; i < 8; ++i)
        d[i] = (short)vptr[(size_t)(kbase + scb + i)*(3*TD) + h*TDH + dh];
      int off = (dh*128 + scb*2) ^ ((dh & 7) << 4);
      *(short8*)&Vs[off] = d;
    }
    __syncthreads();
    // scores: 16 q rows x 64 kv cols per wave
    f32x4 sc[4];
    #pragma unroll
    for (int nj = 0; nj < 4; ++nj) {
      int row = nj*16 + lq;
      int sw = (row & 7) << 4;
      short8 b0 = *(const short8*)&Ks[(row*128 + lg*16) ^ sw];
      short8 b1 = *(const short8*)&Ks[(row*128 + 64 + lg*16) ^ sw];
      f32x4 c = {};
      c = MFMA_BF16(aq0, b0, c);
      c = MFMA_BF16(aq1, b1, c);
      sc[nj] = c;
    }
    // online softmax (lane handles q rows lg*4+r; reduce across 16-lane group)
    float mn[4], al[4];
    #pragma unroll
    for (int r = 0; r < 4; ++r) {
      float x = fmaxf(fmaxf(sc[0][r], sc[1][r]), fmaxf(sc[2][r], sc[3][r]));
      #pragma unroll
      for (int o = 1; o < 16; o <<= 1) x = fmaxf(x, __shfl_xor(x, o));
      mn[r] = fmaxf(rm[r], x);
      al[r] = __expf(rm[r] - mn[r]);
      rm[r] = mn[r];
    }
    #pragma unroll
    for (int nj = 0; nj < 4; ++nj)
      #pragma unroll
      for (int r = 0; r < 4; ++r)
        sc[nj][r] = __expf(sc[nj][r] - mn[r]);
    #pragma unroll
    for (int r = 0; r < 4; ++r) {
      float x = sc[0][r] + sc[1][r] + sc[2][r] + sc[3][r];
      #pragma unroll
      for (int o = 1; o < 16; o <<= 1) x += __shfl_xor(x, o);
      rl[r] = rl[r] * al[r] + x;
    }
    #pragma unroll
    for (int d0 = 0; d0 < 4; ++d0)
      #pragma unroll
      for (int r = 0; r < 4; ++r)
        oacc[d0][r] *= al[r];
    // write P (C-layout) to per-wave LDS, re-read as A-fragments
    #pragma unroll
    for (int nj = 0; nj < 4; ++nj)
      #pragma unroll
      for (int r = 0; r < 4; ++r) {
        int row = lg*4 + r;
        int off = (row*128 + (nj*16 + lq)*2) ^ ((row & 7) << 4);
        *(short*)&Ps[w][off] = (short)f2bf(sc[nj][r]);
      }
    short8 pa0, pa1;
    {
      int sw = (lq & 7) << 4;
      pa0 = *(const short8*)&Ps[w][(lq*128 + lg*16) ^ sw];
      pa1 = *(const short8*)&Ps[w][(lq*128 + 64 + lg*16) ^ sw];
    }
    // PV
    #pragma unroll
    for (int d0 = 0; d0 < 4; ++d0) {
      int row = d0*16 + lq;
      int sw = (row & 7) << 4;
      short8 b0 = *(const short8*)&Vs[(row*128 + lg*16) ^ sw];
      short8 b1 = *(const short8*)&Vs[(row*128 + 64 + lg*16) ^ sw];
      oacc[d0] = MFMA_BF16(pa0, b0, oacc[d0]);
      oacc[d0] = MFMA_BF16(pa1, b1, oacc[d0]);
    }
  }
  #pragma unroll
  for (int d0 = 0; d0 < 4; ++d0)
    #pragma unroll
    for (int r = 0; r < 4; ++r) {
      int row = b*TS + qt*64 + w*16 + lg*4 + r;
      float val = oacc[d0][r] / rl[r];
      y[(size_t)row*TD + h*TDH + d0*16 + lq] = f2bf(val);
    }
}

extern "C" void kernel_launch(void* const* d_in, const int* in_sizes, int n_in,
                              void* d_out, int out_size, void* d_ws, size_t ws_size,
                              hipStream_t stream) {
  const float* x_in = (const float*)d_in[0];
  const float* ln1w = (const float*)d_in[1];
  const float* ln1b = (const float*)d_in[2];
  const float* wqkv = (const float*)d_in[3];
  const float* bqkv = (const float*)d_in[4];
  const float* wo   = (const float*)d_in[5];
  const float* bo   = (const float*)d_in[6];
  const float* ln2w = (const float*)d_in[7];
  const float* ln2b = (const float*)d_in[8];
  const float* w1   = (const float*)d_in[9];
  const float* b1   = (const float*)d_in[10];
  const float* w2   = (const float*)d_in[11];
  const float* b2   = (const float*)d_in[12];
  const float* wout = (const float*)d_in[13];
  const float* bout = (const float*)d_in[14];
  const float* flnw = (const float*)d_in[15];
  const float* flnb = (const float*)d_in[16];

  char* ws = (char*)d_ws;
  size_t off = 0;
  auto alloc = [&](size_t bytes) -> void* {
    void* p = ws + off;
    off += (bytes + 255) & ~(size_t)255;
    return p;
  };
  // per-layer weight buffers (stream-serial reuse across layers)
  unsigned short* wqkv_t = (unsigned short*)alloc((size_t)3*TD*TD*2);
  unsigned short* wo_t   = (unsigned short*)alloc((size_t)TD*TD*2);
  unsigned short* w1_t   = (unsigned short*)alloc((size_t)TMLP*TD*2);
  unsigned short* w2_t   = (unsigned short*)alloc((size_t)TMLP*TD*2);
  unsigned short* wout_t = (unsigned short*)alloc((size_t)TD*TMLP*2);
  float*          x      = (float*)alloc((size_t)TM*TD*4);
  unsigned short* nrm    = (unsigned short*)alloc((size_t)TM*TD*2);
  unsigned short* u1     = (unsigned short*)alloc((size_t)TM*TMLP*2); // qkv | mlp-a
  unsigned short* qbuf   = (unsigned short*)alloc((size_t)TM*TD*2);
  unsigned short* kbuf   = (unsigned short*)alloc((size_t)TM*TD*2);
  unsigned short* u2     = (unsigned short*)alloc((size_t)TM*TMLP*2); // y | mlp-g
  float4*         tab    = (float4*)alloc((size_t)TS*32*sizeof(float4));
  // total ~143.3 MB

  dim3 blk256(256);
  dim3 tblk(32, 8);
  te_tab<<<dim3(TS*32/256), blk256, 0, stream>>>(tab);
  hipMemcpyAsync(x, x_in, (size_t)TM*TD*4, hipMemcpyDeviceToDevice, stream);

  for (int l = 0; l < TL; ++l) {
    te_transpose_cvt<<<dim3(3*TD/32, TD/32), tblk, 0, stream>>>(
        wqkv + (size_t)l*TD*3*TD, wqkv_t, TD, 3*TD);
    te_transpose_cvt<<<dim3(TD/32, TD/32), tblk, 0, stream>>>(
        wo + (size_t)l*TD*TD, wo_t, TD, TD);
    te_transpose_cvt<<<dim3(TMLP/32, TD/32), tblk, 0, stream>>>(
        w1 + (size_t)l*TD*TMLP, w1_t, TD, TMLP);
    te_transpose_cvt<<<dim3(TMLP/32, TD/32), tblk, 0, stream>>>(
        w2 + (size_t)l*TD*TMLP, w2_t, TD, TMLP);
    te_transpose_cvt<<<dim3(TD/32, TMLP/32), tblk, 0, stream>>>(
        wout + (size_t)l*TMLP*TD, wout_t, TMLP, TD);

    te_ln<1><<<dim3(TM), blk256, 0, stream>>>(x, ln1w + l*TD, ln1b + l*TD, nrm);
    te_gemm<0><<<dim3(TM/128, 3*TD/128), blk256, 0, stream>>>(
        nrm, wqkv_t, bqkv + l*3*TD, nullptr, nullptr, u1, TM, 3*TD, TD);
    te_rope<<<dim3(TM*TH*32/256), blk256, 0, stream>>>(u1, tab, qbuf, kbuf);
    te_attn<<<dim3(TS/64, TB*TH), blk256, 0, stream>>>(qbuf, kbuf, u1, u2);
    te_gemm<1><<<dim3(TM/128, TD/128), blk256, 0, stream>>>(
        u2, wo_t, bo + l*TD, x, nullptr, x, TM, TD, TD);
    te_ln<1><<<dim3(TM), blk256, 0, stream>>>(x, ln2w + l*TD, ln2b + l*TD, nrm);
    te_gemm<0><<<dim3(TM/128, TMLP/128), blk256, 0, stream>>>(
        nrm, w1_t, b1 + l*TMLP, nullptr, nullptr, u1, TM, TMLP, TD);
    te_gemm<2><<<dim3(TM/128, TMLP/128), blk256, 0, stream>>>(
        nrm, w2_t, b2 + l*TMLP, nullptr, u1, u2, TM, TMLP, TD);
    te_gemm<1><<<dim3(TM/128, TD/128), blk256, 0, stream>>>(
        u2, wout_t, bout + l*TD, x, nullptr, x, TM, TD, TMLP);
  }
  te_ln<0><<<dim3(TM), blk256, 0, stream>>>(x, flnw, flnb, (float*)d_out);

  (void)in_sizes; (void)n_in; (void)out_size; (void)ws_size;
}

// Round 7
// 1588.725 us; speedup vs baseline: 1.2135x; 1.0863x over previous
//
#include <hip/hip_runtime.h>
#include <hip/hip_bf16.h>
#include <math.h>

// Transformer encoder, B=4 S=1024 D=1024 H=16 DH=64 L=4 MLP=4096.
// bf16 MFMA (16x16x32) for all GEMMs + attention; fp32 LN/RoPE/softmax/residual.
// R2: GEMM BK=64 double-buffered 2-phase + chunk-XOR LDS swizzle.
// R3: attention rebuilt: pre-transposed V^T global buffer, global_load_lds
//     double-buffered K/V staging, XCD-grouped grid, exp2-domain softmax.
// R4: fused dual MLP GEMM (w1/w2 interleaved 16-col groups, in-register silu*g).
// R5: fused MLP GEMM widened to 256x256 tile (8 waves, BK=32, 64KB LDS).
// R6: frozen (infra timeout streak); full audit pass of R3-R5, no code change.

#define TD 1024
#define TH 16
#define TDH 64
#define TL 4
#define TMLP 4096
#define TB 4
#define TS 1024
#define TM (TB*TS)  // 4096 rows

#define LOG2E 1.4426950408889634f

typedef __attribute__((ext_vector_type(8))) short short8;
typedef __attribute__((ext_vector_type(4))) float f32x4;
typedef __attribute__((ext_vector_type(4))) unsigned short us4;
typedef __attribute__((ext_vector_type(2))) unsigned short us2;

__device__ __forceinline__ float bf2f(unsigned short u) {
  union { unsigned int i; float f; } x; x.i = ((unsigned int)u) << 16; return x.f;
}
// round-to-nearest-even f32 -> bf16 (finite inputs only)
__device__ __forceinline__ unsigned short f2bf(float f) {
  unsigned int x = __float_as_uint(f);
  unsigned int r = (x + 0x7FFFu + ((x >> 16) & 1u)) >> 16;
  return (unsigned short)r;
}

#if defined(__has_builtin)
#if __has_builtin(__builtin_amdgcn_global_load_lds)
#define TE_HAS_GLL 1
#endif
#endif

__device__ __forceinline__ void stage16(void* lds, const void* g) {
#ifdef TE_HAS_GLL
  __builtin_amdgcn_global_load_lds(
      (const __attribute__((address_space(1))) void*)g,
      (__attribute__((address_space(3))) void*)lds, 16, 0, 0);
#else
  *(short8*)lds = *(const short8*)g;   // fallback: reg round-trip
#endif
}

#define MFMA_BF16(a,b,c) __builtin_amdgcn_mfma_f32_16x16x32_bf16((a),(b),(c),0,0,0)

// ---------------- RoPE / xpos tables: tab[s*32+i] = {cos, sin, scale*0.125*log2e, 1/scale}
__global__ __launch_bounds__(256)
void te_tab(float4* __restrict__ tab) {
  int idx = blockIdx.x * 256 + threadIdx.x;   // TS*32 = 32768
  int s = idx >> 5, i = idx & 31;
  float inv = powf(10000.0f, -(2.0f * (float)i) / 64.0f);
  float fr = (float)s * inv;
  float c = cosf(fr), sn = sinf(fr);
  float base = (2.0f * (float)i + 0.4f * 64.0f) / (1.4f * 64.0f);
  float p = ((float)s - 512.0f) / 512.0f;
  float scl = powf(base, p);
  float4 t;
  t.x = c; t.y = sn; t.z = scl * 0.125f * LOG2E; t.w = 1.0f / scl;
  tab[idx] = t;
}

// ---------------- weight convert + transpose: W[K][N] f32 -> Wt[N][K] bf16
__global__ __launch_bounds__(256)
void te_transpose_cvt(const float* __restrict__ src, unsigned short* __restrict__ dst,
                      int K, int N) {
  __shared__ float tile[32][33];
  int n0 = blockIdx.x * 32, k0 = blockIdx.y * 32;
  int tx = threadIdx.x, ty = threadIdx.y;
  #pragma unroll
  for (int j = 0; j < 4; ++j)
    tile[ty + 8*j][tx] = src[(size_t)(k0 + ty + 8*j) * N + n0 + tx];
  __syncthreads();
  #pragma unroll
  for (int j = 0; j < 4; ++j)
    dst[(size_t)(n0 + ty + 8*j) * K + k0 + tx] = f2bf(tile[tx][ty + 8*j]);
}

// ---------------- dual weight convert+transpose for fused MLP:
// w1,w2 [K][N] f32 -> Wt[2N][K] bf16, row R = (n>>4)*32 + part*16 + (n&15)
__global__ __launch_bounds__(256)
void te_transpose_cvt2(const float* __restrict__ src1, const float* __restrict__ src2,
                       unsigned short* __restrict__ dst, int K, int N) {
  __shared__ float tile[32][33];
  const float* src = blockIdx.z ? src2 : src1;
  int part = blockIdx.z;
  int n0 = blockIdx.x * 32, k0 = blockIdx.y * 32;
  int tx = threadIdx.x, ty = threadIdx.y;
  #pragma unroll
  for (int j = 0; j < 4; ++j)
    tile[ty + 8*j][tx] = src[(size_t)(k0 + ty + 8*j) * N + n0 + tx];
  __syncthreads();
  #pragma unroll
  for (int j = 0; j < 4; ++j) {
    int n = n0 + ty + 8*j;
    int R = ((n >> 4) << 5) + part * 16 + (n & 15);
    dst[(size_t)R * K + k0 + tx] = f2bf(tile[tx][ty + 8*j]);
  }
}

// ---------------- V transpose: qkv[M][3D] v-columns -> vt[bh][dh][s] bf16
__global__ __launch_bounds__(256)
void te_vt(const unsigned short* __restrict__ qkv, unsigned short* __restrict__ vt) {
  __shared__ unsigned short tile[32][34];
  int s0 = blockIdx.x * 32, c0 = blockIdx.y * 32, b = blockIdx.z;
  int tx = threadIdx.x, ty = threadIdx.y;
  #pragma unroll
  for (int j = 0; j < 4; ++j)
    tile[ty + 8*j][tx] = qkv[(size_t)(b*TS + s0 + ty + 8*j) * (3*TD) + 2*TD + c0 + tx];
  __syncthreads();
  #pragma unroll
  for (int j = 0; j < 4; ++j) {
    int col = c0 + ty + 8*j;               // h*64+dh
    vt[(size_t)(b*TH + (col >> 6)) * (TDH*TS) + (size_t)(col & 63) * TS + s0 + tx] =
        tile[tx][ty + 8*j];
  }
}

// ---------------- LayerNorm over D=1024, one block per row
template<int OUTBF>  // 1: bf16 out, 0: f32 out
__global__ __launch_bounds__(256)
void te_ln(const float* __restrict__ in, const float* __restrict__ w,
           const float* __restrict__ b, void* __restrict__ outp) {
  int row = blockIdx.x, t = threadIdx.x;
  float4 v = ((const float4*)(in + (size_t)row * TD))[t];
  float s = v.x + v.y + v.z + v.w;
  float sq = v.x*v.x + v.y*v.y + v.z*v.z + v.w*v.w;
  #pragma unroll
  for (int o = 1; o < 64; o <<= 1) { s += __shfl_xor(s, o); sq += __shfl_xor(sq, o); }
  __shared__ float red[8];
  int wv = t >> 6;
  if ((t & 63) == 0) { red[wv] = s; red[4 + wv] = sq; }
  __syncthreads();
  s  = red[0] + red[1] + red[2] + red[3];
  sq = red[4] + red[5] + red[6] + red[7];
  float mean = s * (1.0f / TD);
  float rstd = rsqrtf(sq * (1.0f / TD) - mean * mean + 1e-5f);
  float4 w4 = ((const float4*)w)[t];
  float4 b4 = ((const float4*)b)[t];
  float r0 = (v.x - mean) * rstd * w4.x + b4.x;
  float r1 = (v.y - mean) * rstd * w4.y + b4.y;
  float r2 = (v.z - mean) * rstd * w4.z + b4.z;
  float r3 = (v.w - mean) * rstd * w4.w + b4.w;
  if (OUTBF) {
    us4 pk; pk[0] = f2bf(r0); pk[1] = f2bf(r1); pk[2] = f2bf(r2); pk[3] = f2bf(r3);
    ((us4*)outp)[(size_t)row * (TD/4) + t] = pk;
  } else {
    float4 o; o.x = r0; o.y = r1; o.z = r2; o.w = r3;
    ((float4*)outp)[(size_t)row * (TD/4) + t] = o;
  }
}

// ---------------- GEMM: C[M,N] = A[M,K](bf16) @ Bt[N,K](bf16)^T
// 128x128 tile, BK=64, double-buffered LDS, 2-phase schedule.
// MODE 0: out_bf16 = acc + bias
// MODE 1: out_f32  = resid + acc + bias
template<int MODE>
__global__ __launch_bounds__(256)
void te_gemm(const unsigned short* __restrict__ A, const unsigned short* __restrict__ Bt,
             const float* __restrict__ bias, const float* resid,
             const unsigned short* __restrict__ gate, void* outp,
             int M, int N, int K) {
  __shared__ short As[2][128 * 64];
  __shared__ short Bs[2][128 * 64];
  int bm = blockIdx.x, bn = blockIdx.y;
  int t = threadIdx.x;
  int lane = t & 63, w = t >> 6;
  int wr = w >> 1, wc = w & 1;
  int lr = lane & 15, lk = lane >> 4;
  f32x4 acc[4][4] = {};

  const short* Abase = (const short*)A + (size_t)(bm * 128) * K;
  const short* Bbase = (const short*)Bt + (size_t)(bn * 128) * K;
  int srow[4], scol[4];
  #pragma unroll
  for (int j = 0; j < 4; ++j) {
    int m = j * 256 + t;
    int r = m >> 3, c = m & 7;
    srow[j] = r;
    scol[j] = (c ^ (r & 7)) * 8;
  }

  auto stage_tile = [&](int buf, int k0) {
    #pragma unroll
    for (int j = 0; j < 4; ++j) {
      stage16(&As[buf][j * 2048 + t * 8], Abase + (size_t)srow[j] * K + k0 + scol[j]);
      stage16(&Bs[buf][j * 2048 + t * 8], Bbase + (size_t)srow[j] * K + k0 + scol[j]);
    }
  };

  auto compute_tile = [&](int buf) {
    #pragma unroll
    for (int ks = 0; ks < 2; ++ks) {
      short8 af[4], bfv[4];
      #pragma unroll
      for (int mi = 0; mi < 4; ++mi) {
        int row = wr * 64 + mi * 16 + lr;
        int cc = (ks * 4 + lk) ^ (row & 7);
        af[mi] = *(const short8*)&As[buf][row * 64 + cc * 8];
      }
      #pragma unroll
      for (int nj = 0; nj < 4; ++nj) {
        int row = wc * 64 + nj * 16 + lr;
        int cc = (ks * 4 + lk) ^ (row & 7);
        bfv[nj] = *(const short8*)&Bs[buf][row * 64 + cc * 8];
      }
      #pragma unroll
      for (int mi = 0; mi < 4; ++mi)
        #pragma unroll
        for (int nj = 0; nj < 4; ++nj)
          acc[mi][nj] = MFMA_BF16(af[mi], bfv[nj], acc[mi][nj]);
    }
  };

  int nk = K >> 6;
  stage_tile(0, 0);
  __syncthreads();
  int cur = 0;
  for (int kt = 0; kt < nk; ++kt) {
    if (kt + 1 < nk) stage_tile(cur ^ 1, (kt + 1) << 6);
    compute_tile(cur);
    __syncthreads();
    cur ^= 1;
  }

  #pragma unroll
  for (int mi = 0; mi < 4; ++mi) {
    #pragma unroll
    for (int nj = 0; nj < 4; ++nj) {
      int col = bn*128 + wc*64 + nj*16 + lr;
      float bv = bias[col];
      #pragma unroll
      for (int r = 0; r < 4; ++r) {
        int row = bm*128 + wr*64 + mi*16 + lk*4 + r;
        size_t o = (size_t)row * N + col;
        float val = acc[mi][nj][r] + bv;
        if (MODE == 0) {
          ((unsigned short*)outp)[o] = f2bf(val);
        } else if (MODE == 1) {
          ((float*)outp)[o] = resid[o] + val;
        }
      }
    }
  }
  (void)gate;
}

// ---------------- fused dual-MLP GEMM: 256x256 tile, 8 waves, BK=32, 2-phase.
// Bt rows interleave w1/w2 in 16-col groups (te_transpose_cvt2 layout).
// out_bf16[TM][TMLP] = silu(h@w1+b1) * (h@w2+b2).
__global__ __launch_bounds__(512)
void te_gemm_mlp(const unsigned short* __restrict__ A, const unsigned short* __restrict__ Bt,
                 const float* __restrict__ b1p, const float* __restrict__ b2p,
                 unsigned short* __restrict__ outp, int K) {
  __shared__ short As[2][256 * 32];
  __shared__ short Bs[2][256 * 32];
  int bm = blockIdx.x, bn = blockIdx.y;
  int t = threadIdx.x;
  int lane = t & 63, w = t >> 6;       // 8 waves
  int wr = w >> 2, wc = w & 3;         // 2 x 4
  int lr = lane & 15, lk = lane >> 4;
  f32x4 acc[8][4] = {};

  const short* Abase = (const short*)A + (size_t)(bm * 256) * K;
  const short* Bbase = (const short*)Bt + (size_t)(bn * 256) * K;
  // tile [256][32] shorts = 1024 chunks of 16B; 2 chunks/thread.
  // chunk m: row = m>>2, c = m&3; source pre-swizzled c^(row&3).
  int srow[2], scol[2];
  #pragma unroll
  for (int j = 0; j < 2; ++j) {
    int m = j * 512 + t;
    int r = m >> 2, c = m & 3;
    srow[j] = r;
    scol[j] = (c ^ (r & 3)) * 8;
  }

  auto stage_tile = [&](int buf, int k0) {
    #pragma unroll
    for (int j = 0; j < 2; ++j) {
      stage16(&As[buf][j * 4096 + t * 8], Abase + (size_t)srow[j] * K + k0 + scol[j]);
      stage16(&Bs[buf][j * 4096 + t * 8], Bbase + (size_t)srow[j] * K + k0 + scol[j]);
    }
  };

  auto compute_tile = [&](int buf) {
    short8 af[8], bfv[4];
    #pragma unroll
    for (int mi = 0; mi < 8; ++mi) {
      int row = wr * 128 + mi * 16 + lr;
      int cc = lk ^ (row & 3);
      af[mi] = *(const short8*)&As[buf][row * 32 + cc * 8];
    }
    #pragma unroll
    for (int nj = 0; nj < 4; ++nj) {
      int row = wc * 64 + nj * 16 + lr;
      int cc = lk ^ (row & 3);
      bfv[nj] = *(const short8*)&Bs[buf][row * 32 + cc * 8];
    }
    #pragma unroll
    for (int mi = 0; mi < 8; ++mi)
      #pragma unroll
      for (int nj = 0; nj < 4; ++nj)
        acc[mi][nj] = MFMA_BF16(af[mi], bfv[nj], acc[mi][nj]);
  };

  int nk = K >> 5;
  stage_tile(0, 0);
  __syncthreads();
  int cur = 0;
  for (int kt = 0; kt < nk; ++kt) {
    if (kt + 1 < nk) stage_tile(cur ^ 1, (kt + 1) << 5);
    compute_tile(cur);
    __syncthreads();
    cur ^= 1;
  }

  // acc cols: even nj = w1-product (a), odd nj = w2-product (g), same mlp col.
  #pragma unroll
  for (int mi = 0; mi < 8; ++mi) {
    #pragma unroll
    for (int njp = 0; njp < 2; ++njp) {
      int mcol = bn*128 + wc*32 + njp*16 + lr;
      float bva = b1p[mcol];
      float bvg = b2p[mcol];
      #pragma unroll
      for (int r = 0; r < 4; ++r) {
        int row = bm*256 + wr*128 + mi*16 + lk*4 + r;
        float a = acc[mi][njp*2][r] + bva;
        float g = acc[mi][njp*2+1][r] + bvg;
        float sg = a / (1.0f + __expf(-a));
        outp[(size_t)row * TMLP + mcol] = f2bf(sg * g);
      }
    }
  }
}

// ---------------- RoPE: qkv bf16 [M][3D] -> roped q,k bf16 [M][D]
__global__ __launch_bounds__(256)
void te_rope(const unsigned short* __restrict__ qkv, const float4* __restrict__ tab,
             unsigned short* __restrict__ qb, unsigned short* __restrict__ kb) {
  int idx = blockIdx.x * 256 + threadIdx.x;  // TM*TH*32
  int i = idx & 31;
  int h = (idx >> 5) & 15;
  int row = idx >> 9;
  int s = row & (TS - 1);
  float4 t4 = tab[(s << 5) + i];
  size_t base = (size_t)row * (3*TD) + h * TDH + 2*i;
  us2 qp = *(const us2*)&qkv[base];
  us2 kp = *(const us2*)&qkv[base + TD];
  float qe = bf2f(qp[0]), qo = bf2f(qp[1]);
  float ke = bf2f(kp[0]), ko = bf2f(kp[1]);
  size_t ob = (size_t)row * TD + h * TDH + 2*i;
  us2 qo2, ko2;
  qo2[0] = f2bf((qe * t4.x - qo * t4.y) * t4.z);
  qo2[1] = f2bf((qo * t4.x + qe * t4.y) * t4.z);
  ko2[0] = f2bf((ke * t4.x - ko * t4.y) * t4.w);
  ko2[1] = f2bf((ko * t4.x + ke * t4.y) * t4.w);
  *(us2*)&qb[ob] = qo2;
  *(us2*)&kb[ob] = ko2;
}

// ---------------- flash attention: 1D grid, XCD-grouped (b,h); 4 waves x 16 q rows.
// K/V^T staged via global_load_lds, double-buffered, chunk-XOR swizzle
// (pre-swizzled global source + swizzled ds_read). Softmax in exp2 domain
// (log2e folded into q scale).
__global__ __launch_bounds__(256)
void te_attn(const unsigned short* __restrict__ qb, const unsigned short* __restrict__ kb,
             const unsigned short* __restrict__ vt, unsigned short* __restrict__ y) {
  __shared__ short Ks[2][64 * 64];   // [kv][dh] bf16, swizzled
  __shared__ short Vs[2][64 * 64];   // [dh][kv] bf16, swizzled
  __shared__ char Ps[4][2048];       // per-wave P [16 q][64 kv] bf16, swizzled
  int bid = blockIdx.x;              // 0..1023
  int xcd = bid & 7, j = bid >> 3;
  int qt = j & 15;                   // 16 q-tiles of one (b,h) consecutive per XCD
  int bh = (j >> 4) * 8 + xcd;       // 0..63
  int b = bh >> 4, h = bh & 15;
  int t = threadIdx.x, lane = t & 63, w = t >> 6;
  int lq = lane & 15, lg = lane >> 4;

  int qrow = b*TS + qt*64 + w*16 + lq;
  short8 aq0 = *(const short8*)&qb[(size_t)qrow*TD + h*TDH + lg*8];
  short8 aq1 = *(const short8*)&qb[(size_t)qrow*TD + h*TDH + 32 + lg*8];

  const unsigned short* kbase_p = kb + (size_t)(b*TS) * TD + h * TDH;  // + s*TD + dh
  const unsigned short* vbase_p = vt + (size_t)bh * (TDH*TS);          // + dh*TS + s

  f32x4 oacc[4] = {};
  float rm[4] = {-3e38f, -3e38f, -3e38f, -3e38f};
  float rl[4] = {0.f, 0.f, 0.f, 0.f};

  // staging map: chunk m = j2*256 + t; row = m>>3 (0..63), c = m&7; src chunk c^(row&7)
  int srow[2], scol[2];
  #pragma unroll
  for (int j2 = 0; j2 < 2; ++j2) {
    int m = j2 * 256 + t;
    int r = m >> 3, c = m & 7;
    srow[j2] = r;
    scol[j2] = (c ^ (r & 7)) * 8;
  }

  auto stage_kv = [&](int buf, int kt) {
    int s0 = kt * 64;
    #pragma unroll
    for (int j2 = 0; j2 < 2; ++j2) {
      stage16(&Ks[buf][j2 * 2048 + t * 8],
              kbase_p + (size_t)(s0 + srow[j2]) * TD + scol[j2]);
      stage16(&Vs[buf][j2 * 2048 + t * 8],
              vbase_p + (size_t)srow[j2] * TS + s0 + scol[j2]);
    }
  };

  stage_kv(0, 0);
  __syncthreads();
  int cur = 0;
  for (int kt = 0; kt < TS/64; ++kt) {
    if (kt + 1 < TS/64) stage_kv(cur ^ 1, kt + 1);
    // scores: 16 q rows x 64 kv cols per wave
    f32x4 sc[4];
    #pragma unroll
    for (int nj = 0; nj < 4; ++nj) {
      int row = nj*16 + lq;
      int sw = (row & 7);
      short8 b0 = *(const short8*)&Ks[cur][row * 64 + (lg ^ sw) * 8];
      short8 b1 = *(const short8*)&Ks[cur][row * 64 + ((4 + lg) ^ sw) * 8];
      f32x4 c = {};
      c = MFMA_BF16(aq0, b0, c);
      c = MFMA_BF16(aq1, b1, c);
      sc[nj] = c;
    }
    // online softmax in exp2 domain (lane owns q rows lg*4+r)
    float mn[4], al[4];
    #pragma unroll
    for (int r = 0; r < 4; ++r) {
      float x = fmaxf(fmaxf(sc[0][r], sc[1][r]), fmaxf(sc[2][r], sc[3][r]));
      #pragma unroll
      for (int o = 1; o < 16; o <<= 1) x = fmaxf(x, __shfl_xor(x, o));
      mn[r] = fmaxf(rm[r], x);
      al[r] = exp2f(rm[r] - mn[r]);
      rm[r] = mn[r];
    }
    #pragma unroll
    for (int nj = 0; nj < 4; ++nj)
      #pragma unroll
      for (int r = 0; r < 4; ++r)
        sc[nj][r] = exp2f(sc[nj][r] - mn[r]);
    #pragma unroll
    for (int r = 0; r < 4; ++r) {
      float x = sc[0][r] + sc[1][r] + sc[2][r] + sc[3][r];
      #pragma unroll
      for (int o = 1; o < 16; o <<= 1) x += __shfl_xor(x, o);
      rl[r] = rl[r] * al[r] + x;
    }
    #pragma unroll
    for (int d0 = 0; d0 < 4; ++d0)
      #pragma unroll
      for (int r = 0; r < 4; ++r)
        oacc[d0][r] *= al[r];
    // write P (C-layout) to per-wave LDS, re-read as A-fragments
    #pragma unroll
    for (int nj = 0; nj < 4; ++nj)
      #pragma unroll
      for (int r = 0; r < 4; ++r) {
        int row = lg*4 + r;
        int off = (row*128 + (nj*16 + lq)*2) ^ ((row & 7) << 4);
        *(short*)&Ps[w][off] = (short)f2bf(sc[nj][r]);
      }
    short8 pa0, pa1;
    {
      int sw = (lq & 7) << 4;
      pa0 = *(const short8*)&Ps[w][(lq*128 + lg*16) ^ sw];
      pa1 = *(const short8*)&Ps[w][(lq*128 + 64 + lg*16) ^ sw];
    }
    // PV: V^T rows are dh, cols kv
    #pragma unroll
    for (int d0 = 0; d0 < 4; ++d0) {
      int row = d0*16 + lq;
      int sw = (row & 7);
      short8 b0 = *(const short8*)&Vs[cur][row * 64 + (lg ^ sw) * 8];
      short8 b1 = *(const short8*)&Vs[cur][row * 64 + ((4 + lg) ^ sw) * 8];
      oacc[d0] = MFMA_BF16(pa0, b0, oacc[d0]);
      oacc[d0] = MFMA_BF16(pa1, b1, oacc[d0]);
    }
    __syncthreads();
    cur ^= 1;
  }
  #pragma unroll
  for (int d0 = 0; d0 < 4; ++d0)
    #pragma unroll
    for (int r = 0; r < 4; ++r) {
      int row = b*TS + qt*64 + w*16 + lg*4 + r;
      float val = oacc[d0][r] / rl[r];
      y[(size_t)row*TD + h*TDH + d0*16 + lq] = f2bf(val);
    }
}

extern "C" void kernel_launch(void* const* d_in, const int* in_sizes, int n_in,
                              void* d_out, int out_size, void* d_ws, size_t ws_size,
                              hipStream_t stream) {
  const float* x_in = (const float*)d_in[0];
  const float* ln1w = (const float*)d_in[1];
  const float* ln1b = (const float*)d_in[2];
  const float* wqkv = (const float*)d_in[3];
  const float* bqkv = (const float*)d_in[4];
  const float* wo   = (const float*)d_in[5];
  const float* bo   = (const float*)d_in[6];
  const float* ln2w = (const float*)d_in[7];
  const float* ln2b = (const float*)d_in[8];
  const float* w1   = (const float*)d_in[9];
  const float* b1   = (const float*)d_in[10];
  const float* w2   = (const float*)d_in[11];
  const float* b2   = (const float*)d_in[12];
  const float* wout = (const float*)d_in[13];
  const float* bout = (const float*)d_in[14];
  const float* flnw = (const float*)d_in[15];
  const float* flnb = (const float*)d_in[16];

  char* ws = (char*)d_ws;
  size_t off = 0;
  auto alloc = [&](size_t bytes) -> void* {
    void* p = ws + off;
    off += (bytes + 255) & ~(size_t)255;
    return p;
  };
  // per-layer weight buffers (stream-serial reuse across layers)
  unsigned short* wqkv_t = (unsigned short*)alloc((size_t)3*TD*TD*2);
  unsigned short* wo_t   = (unsigned short*)alloc((size_t)TD*TD*2);
  unsigned short* w12_t  = (unsigned short*)alloc((size_t)2*TMLP*TD*2); // interleaved
  unsigned short* wout_t = (unsigned short*)alloc((size_t)TD*TMLP*2);
  float*          x      = (float*)alloc((size_t)TM*TD*4);
  unsigned short* nrm    = (unsigned short*)alloc((size_t)TM*TD*2);
  unsigned short* u1     = (unsigned short*)alloc((size_t)TM*TMLP*2); // qkv
  unsigned short* qbuf   = (unsigned short*)alloc((size_t)TM*TD*2);
  unsigned short* kbuf   = (unsigned short*)alloc((size_t)TM*TD*2);
  unsigned short* u2     = (unsigned short*)alloc((size_t)TM*TMLP*2); // y | silu-prod
  float4*         tab    = (float4*)alloc((size_t)TS*32*sizeof(float4));
  // vt aliases the second 8MB of u2 (dead during attention phase)
  unsigned short* vtbuf  = u2 + (size_t)TM*TD;

  dim3 blk256(256);
  dim3 tblk(32, 8);
  te_tab<<<dim3(TS*32/256), blk256, 0, stream>>>(tab);
  hipMemcpyAsync(x, x_in, (size_t)TM*TD*4, hipMemcpyDeviceToDevice, stream);

  for (int l = 0; l < TL; ++l) {
    te_transpose_cvt<<<dim3(3*TD/32, TD/32), tblk, 0, stream>>>(
        wqkv + (size_t)l*TD*3*TD, wqkv_t, TD, 3*TD);
    te_transpose_cvt<<<dim3(TD/32, TD/32), tblk, 0, stream>>>(
        wo + (size_t)l*TD*TD, wo_t, TD, TD);
    te_transpose_cvt2<<<dim3(TMLP/32, TD/32, 2), tblk, 0, stream>>>(
        w1 + (size_t)l*TD*TMLP, w2 + (size_t)l*TD*TMLP, w12_t, TD, TMLP);
    te_transpose_cvt<<<dim3(TD/32, TMLP/32), tblk, 0, stream>>>(
        wout + (size_t)l*TMLP*TD, wout_t, TMLP, TD);

    te_ln<1><<<dim3(TM), blk256, 0, stream>>>(x, ln1w + l*TD, ln1b + l*TD, nrm);
    te_gemm<0><<<dim3(TM/128, 3*TD/128), blk256, 0, stream>>>(
        nrm, wqkv_t, bqkv + l*3*TD, nullptr, nullptr, u1, TM, 3*TD, TD);
    te_rope<<<dim3(TM*TH*32/256), blk256, 0, stream>>>(u1, tab, qbuf, kbuf);
    te_vt<<<dim3(TS/32, TD/32, TB), tblk, 0, stream>>>(u1, vtbuf);
    te_attn<<<dim3(TB*TH*(TS/64)), blk256, 0, stream>>>(qbuf, kbuf, vtbuf, u2);
    te_gemm<1><<<dim3(TM/128, TD/128), blk256, 0, stream>>>(
        u2, wo_t, bo + l*TD, x, nullptr, x, TM, TD, TD);
    te_ln<1><<<dim3(TM), blk256, 0, stream>>>(x, ln2w + l*TD, ln2b + l*TD, nrm);
    te_gemm_mlp<<<dim3(TM/256, 2*TMLP/256), dim3(512), 0, stream>>>(
        nrm, w12_t, b1 + l*TMLP, b2 + l*TMLP, u2, TD);
    te_gemm<1><<<dim3(TM/128, TD/128), blk256, 0, stream>>>(
        u2, wout_t, bout + l*TD, x, nullptr, x, TM, TD, TMLP);
  }
  te_ln<0><<<dim3(TM), blk256, 0, stream>>>(x, flnw, flnb, (float*)d_out);

  (void)in_sizes; (void)n_in; (void)out_size; (void)ws_size;
}